// Round 19
// baseline (172.933 us; speedup 1.0000x reference)
//
#include <hip/hip_runtime.h>

// ObjectMeanDirectAttention — Round 19: no-LDS fast path (R16 fragment loads + R18
// segment scatter). R17 proved coalescing is irrelevant -> direct fragment loads; the
// Xs transpose tile is deleted. Per-q chain: load->cvt->MFMA->shfl->predicated FMA,
// zero LDS in the dependency chain; q-chains fully independent. Scatter multiplier is
// the lane's OWN a (no shfl broadcast). LDS = weights+coefs only (19.2 KB).

#define NGRAPHS 4096
constexpr int LDP = 68;    // f32 LDS stride, final MLP
constexpr int LDU = 132;   // f32 LDS stride, 128-wide u tile
constexpr int LDXS = 72;   // bf16 LDS stride (144B rows) for weight tiles

typedef short bf16x8 __attribute__((ext_vector_type(8)));
typedef float f32x4 __attribute__((ext_vector_type(4)));

union BF8 { bf16x8 v; unsigned u[4]; };

__device__ __forceinline__ unsigned short f2bf(float f) {
    unsigned u = __float_as_uint(f);
    return (unsigned short)((u + 0x7FFFu + ((u >> 16) & 1u)) >> 16);  // RNE
}

__device__ __forceinline__ unsigned cvt_pk_bf16(float lo, float hi) {
    unsigned r;
    asm("v_cvt_pk_bf16_f32 %0, %1, %2" : "=v"(r) : "v"(lo), "v"(hi));
    return r;
}

__device__ __forceinline__ int lower_bound_i(const int* __restrict__ arr, int n, int v) {
    int lo = 0, hi = n;
    while (lo < hi) {
        int mid = (lo + hi) >> 1;
        if (arr[mid] < v) lo = mid + 1; else hi = mid;
    }
    return lo;
}

// one-shot prep: permuted bf16 weights into ws
__global__ __launch_bounds__(256)
void prep_kernel(const float* __restrict__ W1, const float* __restrict__ W2,
                 unsigned short* __restrict__ w1p, unsigned short* __restrict__ w2t) {
    int e = blockIdx.x * 256 + threadIdx.x;     // 0..4095
    int r = e >> 6, k = e & 63;
    int ct = r >> 4, kb = (r >> 2) & 3, reg = r & 3;
    int pi = 32 * (ct >> 1) + 8 * kb + 4 * (ct & 1) + reg;
    w1p[e] = f2bf(W1[k * 64 + pi]);
    w2t[e] = f2bf(W2[k * 64 + r]);
}

// ---------------- attention MLP + weighted scatter ----------------
__global__ __launch_bounds__(256)
void attn_scatter_mfma(const float* __restrict__ x1, const int* __restrict__ batch1, int N1, int nblk1,
                       const float* __restrict__ x2, const int* __restrict__ batch2, int N2,
                       const unsigned short* __restrict__ w1p, const unsigned short* __restrict__ w2t,
                       const float* __restrict__ b1, const float* __restrict__ b2,
                       const float* __restrict__ W3, const float* __restrict__ b3,
                       float* __restrict__ num) {
    __shared__ alignas(16) unsigned short W1L[64 * LDXS];     // bf16, 144B rows (bank-uniform)
    __shared__ alignas(16) unsigned short W2L[64 * LDXS];
    __shared__ alignas(16) float coefF[192];                  // b1 | b2 | W3 (f32)

    const float* x; const int* batch; int N, col_off, blk;
    if ((int)blockIdx.x < nblk1) { x = x1; batch = batch1; N = N1; col_off = 0;  blk = blockIdx.x; }
    else                         { x = x2; batch = batch2; N = N2; col_off = 64; blk = blockIdx.x - nblk1; }

    const int t = threadIdx.x;
    const int w = t >> 6, l = t & 63;
    const int jj = l & 15, kb = l >> 4;    // fragment coords: lane owns node (nbase+jj), feats F_kb
    const int base = blk * 256 + w * 64;   // this wave's 64 nodes

    // ---- stage weights (16 KB) + f32 coefficients into LDS ----
    {
        const uint4* s1 = (const uint4*)w1p;      // 512 chunks of 16B
        const uint4* s2 = (const uint4*)w2t;
#pragma unroll
        for (int r = 0; r < 2; ++r) {
            int e4 = t + 256 * r;                 // 0..511
            int row = e4 >> 3, c4 = e4 & 7;       // row 0..63, 16B-chunk 0..7
            *(uint4*)((char*)W1L + row * 144 + c4 * 16) = s1[e4];
            *(uint4*)((char*)W2L + row * 144 + c4 * 16) = s2[e4];
        }
        if (t < 64)       coefF[t] = b1[t];
        else if (t < 128) coefF[t] = b2[t - 64];
        else if (t < 192) coefF[t] = W3[t - 128];
    }
    __syncthreads();

    // ---- batch ids + boundary ballot (wave-uniform 64-bit mask) ----
    const int gball = batch[min(base + l, N - 1)];
    const int gprev = __shfl_up(gball, 1);
    const unsigned long long bal = __ballot(l > 0 && gball != gprev);

    const float b3v = b3[0];

    // 16 per-lane feature accumulators (features F_kb of the running graph segment)
    float acc16[16];
#pragma unroll
    for (int i = 0; i < 16; ++i) acc16[i] = 0.f;
    int gcur = __shfl(gball, 0);

    // flush helper: reduce over jj-lanes, one atomic per lane (feature f)
    auto flush = [&](int g) {
#pragma unroll
        for (int i = 0; i < 16; ++i) {
            acc16[i] += __shfl_xor(acc16[i], 1);
            acc16[i] += __shfl_xor(acc16[i], 2);
            acc16[i] += __shfl_xor(acc16[i], 4);
            acc16[i] += __shfl_xor(acc16[i], 8);
        }
        float v = acc16[0];
#pragma unroll
        for (int i = 1; i < 16; ++i) v = (jj == i) ? acc16[i] : v;   // static indices
        const int f = (jj < 8) ? (kb * 8 + jj) : (32 + kb * 8 + (jj - 8));
        atomicAdd(&num[(size_t)g * 128 + col_off + f], v);
#pragma unroll
        for (int i = 0; i < 16; ++i) acc16[i] = 0.f;
    };

#pragma unroll
    for (int q = 0; q < 4; ++q) {
        const int nbase = base + q * 16;
        const int row = nbase + jj;

        // ---- fragment loads: lane (jj,kb) holds node jj's feats kb*8..+7 / 32+kb*8..+7 ----
        float4 c0, c1, c2, c3;
        c0 = c1 = c2 = c3 = make_float4(0.f, 0.f, 0.f, 0.f);
        if (row < N) {
            const float* xr = x + (size_t)row * 64;
            c0 = *(const float4*)&xr[kb * 8];
            c1 = *(const float4*)&xr[kb * 8 + 4];
            c2 = *(const float4*)&xr[32 + kb * 8];
            c3 = *(const float4*)&xr[32 + kb * 8 + 4];
        }

        BF8 xb0, xb1;
        xb0.u[0] = cvt_pk_bf16(c0.x, c0.y); xb0.u[1] = cvt_pk_bf16(c0.z, c0.w);
        xb0.u[2] = cvt_pk_bf16(c1.x, c1.y); xb0.u[3] = cvt_pk_bf16(c1.z, c1.w);
        xb1.u[0] = cvt_pk_bf16(c2.x, c2.y); xb1.u[1] = cvt_pk_bf16(c2.z, c2.w);
        xb1.u[2] = cvt_pk_bf16(c3.x, c3.y); xb1.u[3] = cvt_pk_bf16(c3.z, c3.w);

        // ---- layer 1 (swapped): weights from LDS, bias C-init from f32 LDS ----
        unsigned ph[8];
#pragma unroll
        for (int ct = 0; ct < 4; ++ct) {
            const unsigned short* wr = &W1L[(ct * 16 + jj) * LDXS + kb * 8];
            const bf16x8 wf0 = *(const bf16x8*)wr;
            const bf16x8 wf1 = *(const bf16x8*)(wr + 32);
            f32x4 acc = *(const f32x4*)&coefF[32 * (ct >> 1) + 8 * kb + 4 * (ct & 1)];
            acc = __builtin_amdgcn_mfma_f32_16x16x32_bf16(wf0, xb0.v, acc, 0, 0, 0);
            acc = __builtin_amdgcn_mfma_f32_16x16x32_bf16(wf1, xb1.v, acc, 0, 0, 0);
            ph[2 * ct]     = cvt_pk_bf16(fmaxf(acc[0], 0.f), fmaxf(acc[1], 0.f));
            ph[2 * ct + 1] = cvt_pk_bf16(fmaxf(acc[2], 0.f), fmaxf(acc[3], 0.f));
        }
        BF8 bh0, bh1;
        bh0.u[0] = ph[0]; bh0.u[1] = ph[1]; bh0.u[2] = ph[2]; bh0.u[3] = ph[3];
        bh1.u[0] = ph[4]; bh1.u[1] = ph[5]; bh1.u[2] = ph[6]; bh1.u[3] = ph[7];

        // ---- layer 2+3 (swapped): b2/W3 as f32x4 from LDS ----
        float p = 0.f;
#pragma unroll
        for (int ct = 0; ct < 4; ++ct) {
            const unsigned short* wr = &W2L[(ct * 16 + jj) * LDXS + kb * 8];
            const bf16x8 wf0 = *(const bf16x8*)wr;
            const bf16x8 wf1 = *(const bf16x8*)(wr + 32);
            f32x4 acc = { 0.f, 0.f, 0.f, 0.f };
            acc = __builtin_amdgcn_mfma_f32_16x16x32_bf16(wf0, bh0.v, acc, 0, 0, 0);
            acc = __builtin_amdgcn_mfma_f32_16x16x32_bf16(wf1, bh1.v, acc, 0, 0, 0);
            const f32x4 b2v = *(const f32x4*)&coefF[64 + ct * 16 + 4 * kb];
            const f32x4 w3v = *(const f32x4*)&coefF[128 + ct * 16 + 4 * kb];
            p += fmaxf(acc[0] + b2v[0], 0.f) * w3v[0]
               + fmaxf(acc[1] + b2v[1], 0.f) * w3v[1]
               + fmaxf(acc[2] + b2v[2], 0.f) * w3v[2]
               + fmaxf(acc[3] + b2v[3], 0.f) * w3v[3];
        }
        p += __shfl_xor(p, 16);
        p += __shfl_xor(p, 32);
        const float a = p + b3v;     // a[node nbase+jj], held by THIS lane

        // ---- scatter: per-q segment handling (wave-uniform control, own-a multiply) ----
        const unsigned m = (unsigned)((bal >> (q * 16)) & 0xFFFFull);
        if (m == 0u) {
            acc16[0]  += c0.x * a; acc16[1]  += c0.y * a; acc16[2]  += c0.z * a; acc16[3]  += c0.w * a;
            acc16[4]  += c1.x * a; acc16[5]  += c1.y * a; acc16[6]  += c1.z * a; acc16[7]  += c1.w * a;
            acc16[8]  += c2.x * a; acc16[9]  += c2.y * a; acc16[10] += c2.z * a; acc16[11] += c2.w * a;
            acc16[12] += c3.x * a; acc16[13] += c3.y * a; acc16[14] += c3.z * a; acc16[15] += c3.w * a;
        } else {
            unsigned mm = m;
            int pos = 0;
            while (true) {
                const int nxt = mm ? (__ffs(mm) - 1) : 16;
                const float ws = (jj >= pos && jj < nxt) ? a : 0.f;   // own-node predication
                acc16[0]  += c0.x * ws; acc16[1]  += c0.y * ws; acc16[2]  += c0.z * ws; acc16[3]  += c0.w * ws;
                acc16[4]  += c1.x * ws; acc16[5]  += c1.y * ws; acc16[6]  += c1.z * ws; acc16[7]  += c1.w * ws;
                acc16[8]  += c2.x * ws; acc16[9]  += c2.y * ws; acc16[10] += c2.z * ws; acc16[11] += c2.w * ws;
                acc16[12] += c3.x * ws; acc16[13] += c3.y * ws; acc16[14] += c3.z * ws; acc16[15] += c3.w * ws;
                if (nxt == 16) break;
                flush(gcur);
                gcur = __shfl(gball, q * 16 + nxt);
                mm &= mm - 1;
                pos = nxt;
            }
        }
    }

    // ---- final flush ----
    flush(gcur);
}

// ---------------- final MLP (f32, unchanged: negligible time) ----------------
template<int K, int LDAa, int LDBb>
__device__ __forceinline__ void tile_gemm(const float* __restrict__ As,
                                          const float* __restrict__ Bs,
                                          float acc[4][4], int n0, int j0) {
#pragma unroll 4
    for (int k0 = 0; k0 < K; k0 += 4) {
        float4 a[4], wv[4];
#pragma unroll
        for (int i = 0; i < 4; i++) a[i] = *(const float4*)&As[(n0 + i) * LDAa + k0];
#pragma unroll
        for (int kk = 0; kk < 4; kk++) wv[kk] = *(const float4*)&Bs[(k0 + kk) * LDBb + j0];
#pragma unroll
        for (int i = 0; i < 4; i++) {
            const float av0 = a[i].x, av1 = a[i].y, av2 = a[i].z, av3 = a[i].w;
            acc[i][0] += av0 * wv[0].x; acc[i][1] += av0 * wv[0].y; acc[i][2] += av0 * wv[0].z; acc[i][3] += av0 * wv[0].w;
            acc[i][0] += av1 * wv[1].x; acc[i][1] += av1 * wv[1].y; acc[i][2] += av1 * wv[1].z; acc[i][3] += av1 * wv[1].w;
            acc[i][0] += av2 * wv[2].x; acc[i][1] += av2 * wv[2].y; acc[i][2] += av2 * wv[2].z; acc[i][3] += av2 * wv[2].w;
            acc[i][0] += av3 * wv[3].x; acc[i][1] += av3 * wv[3].y; acc[i][2] += av3 * wv[3].z; acc[i][3] += av3 * wv[3].w;
        }
    }
}

__global__ __launch_bounds__(256)
void final_mlp_kernel(const float* __restrict__ num,
                      const int* __restrict__ batch1, int N1,
                      const int* __restrict__ batch2, int N2,
                      const float* __restrict__ W1, const float* __restrict__ b1,  // [128][64]
                      const float* __restrict__ W2, const float* __restrict__ b2,  // [64][64]
                      const float* __restrict__ W3, const float* __restrict__ b3,  // [64][64]
                      float* __restrict__ out) {
    __shared__ float Us[64 * LDU];
    __shared__ float W1s[128 * LDP];
    __shared__ float W2s[64 * LDP];
    __shared__ float W3s[64 * LDP];
    __shared__ float Hs[64 * LDP];
    __shared__ float inv1[64], inv2[64];

    const int t = threadIdx.x;
    const int rowbase = blockIdx.x * 64;

    if (t < 64) {
        int g = rowbase + t;
        int c = lower_bound_i(batch1, N1, g + 1) - lower_bound_i(batch1, N1, g);
        inv1[t] = 1.0f / (float)max(c, 1);
    } else if (t < 128) {
        int g = rowbase + (t - 64);
        int c = lower_bound_i(batch2, N2, g + 1) - lower_bound_i(batch2, N2, g);
        inv2[t - 64] = 1.0f / (float)max(c, 1);
    }

    {
        const float4* W1v = (const float4*)W1;
#pragma unroll
        for (int r = 0; r < 8; r++) {
            int e4 = t + 256 * r;
            int e = e4 * 4;
            int k = e / 64, j = e % 64;
            *(float4*)&W1s[k * LDP + j] = W1v[e4];
        }
        const float4* W2v = (const float4*)W2;
        const float4* W3v = (const float4*)W3;
#pragma unroll
        for (int r = 0; r < 4; r++) {
            int e4 = t + 256 * r;
            int e = e4 * 4;
            int k = e / 64, j = e % 64;
            *(float4*)&W2s[k * LDP + j] = W2v[e4];
            *(float4*)&W3s[k * LDP + j] = W3v[e4];
        }
    }
    __syncthreads();

    {
        const float4* nv = (const float4*)(num + (size_t)rowbase * 128);
#pragma unroll
        for (int r = 0; r < 8; r++) {
            int e4 = t + 256 * r;
            int e = e4 * 4;
            int row = e / 128, col = e % 128;
            float4 v = nv[e4];
            float s = (col < 64) ? inv1[row] : inv2[row];
            v.x *= s; v.y *= s; v.z *= s; v.w *= s;
            *(float4*)&Us[row * LDU + col] = v;
        }
    }
    __syncthreads();

    const int fg = t & 15, ng = t >> 4;
    const int j0 = fg * 4, n0 = ng * 4;

    float acc[4][4];
#pragma unroll
    for (int i = 0; i < 4; i++) { acc[i][0] = 0.f; acc[i][1] = 0.f; acc[i][2] = 0.f; acc[i][3] = 0.f; }
    tile_gemm<128, LDU, LDP>(Us, W1s, acc, n0, j0);
    {
        float4 bb = *(const float4*)&b1[j0];
#pragma unroll
        for (int i = 0; i < 4; i++) {
            float4 hv;
            hv.x = fmaxf(acc[i][0] + bb.x, 0.f);
            hv.y = fmaxf(acc[i][1] + bb.y, 0.f);
            hv.z = fmaxf(acc[i][2] + bb.z, 0.f);
            hv.w = fmaxf(acc[i][3] + bb.w, 0.f);
            *(float4*)&Hs[(n0 + i) * LDP + j0] = hv;
        }
    }
    __syncthreads();

#pragma unroll
    for (int i = 0; i < 4; i++) { acc[i][0] = 0.f; acc[i][1] = 0.f; acc[i][2] = 0.f; acc[i][3] = 0.f; }
    tile_gemm<64, LDP, LDP>(Hs, W2s, acc, n0, j0);
    {
        float4 bb = *(const float4*)&b2[j0];
#pragma unroll
        for (int i = 0; i < 4; i++) {
            float4 hv;
            hv.x = fmaxf(acc[i][0] + bb.x, 0.f);
            hv.y = fmaxf(acc[i][1] + bb.y, 0.f);
            hv.z = fmaxf(acc[i][2] + bb.z, 0.f);
            hv.w = fmaxf(acc[i][3] + bb.w, 0.f);
            *(float4*)&Us[(n0 + i) * LDU + j0] = hv;
        }
    }
    __syncthreads();

#pragma unroll
    for (int i = 0; i < 4; i++) { acc[i][0] = 0.f; acc[i][1] = 0.f; acc[i][2] = 0.f; acc[i][3] = 0.f; }
    tile_gemm<64, LDU, LDP>(Us, W3s, acc, n0, j0);
    {
        float4 bb = *(const float4*)&b3[j0];
#pragma unroll
        for (int i = 0; i < 4; i++) {
            float4 ov;
            ov.x = acc[i][0] + bb.x;
            ov.y = acc[i][1] + bb.y;
            ov.z = acc[i][2] + bb.z;
            ov.w = acc[i][3] + bb.w;
            *(float4*)&out[(size_t)(rowbase + n0 + i) * 64 + j0] = ov;
        }
    }
}

extern "C" void kernel_launch(void* const* d_in, const int* in_sizes, int n_in,
                              void* d_out, int out_size, void* d_ws, size_t ws_size,
                              hipStream_t stream) {
    const float* x1     = (const float*)d_in[0];
    const int*   batch1 = (const int*)d_in[1];
    const float* x2     = (const float*)d_in[2];
    const int*   batch2 = (const int*)d_in[3];
    const float* aW1    = (const float*)d_in[4];
    const float* ab1    = (const float*)d_in[5];
    const float* aW2    = (const float*)d_in[6];
    const float* ab2    = (const float*)d_in[7];
    const float* aW3    = (const float*)d_in[8];
    const float* ab3    = (const float*)d_in[9];
    const float* fW1    = (const float*)d_in[10];
    const float* fb1    = (const float*)d_in[11];
    const float* fW2    = (const float*)d_in[12];
    const float* fb2    = (const float*)d_in[13];
    const float* fW3    = (const float*)d_in[14];
    const float* fb3    = (const float*)d_in[15];

    const int N1 = in_sizes[0] / 64;
    const int N2 = in_sizes[2] / 64;

    // ws layout: [w1p 8KB][w2t 8KB][num f32 4096x128 = 2MB]
    unsigned short* w1p = (unsigned short*)d_ws;
    unsigned short* w2t = w1p + 64 * 64;
    float* num = (float*)((char*)d_ws + 16384);

    prep_kernel<<<dim3(16), dim3(256), 0, stream>>>(aW1, aW2, w1p, w2t);
    hipMemsetAsync(num, 0, (size_t)NGRAPHS * 128 * sizeof(float), stream);

    const int nblk1 = (N1 + 255) / 256;
    const int nblk2 = (N2 + 255) / 256;
    attn_scatter_mfma<<<dim3(nblk1 + nblk2), dim3(256), 0, stream>>>(
        x1, batch1, N1, nblk1, x2, batch2, N2,
        w1p, w2t, ab1, ab2, aW3, ab3, num);
    final_mlp_kernel<<<dim3(NGRAPHS / 64), dim3(256), 0, stream>>>(
        num, batch1, N1, batch2, N2, fW1, fb1, fW2, fb2, fW3, fb3, (float*)d_out);
}

// Round 20
// 130.022 us; speedup vs baseline: 1.3300x; 1.3300x over previous
//
#include <hip/hip_runtime.h>

// ObjectMeanDirectAttention — Round 20: R18 (proven 135us: contiguous loads + LDS
// transpose + per-q segment scatter) + depth-1 prefetch of next q's loads.
// R19 lesson: scattered fragment loads cost ~35us once the serial slow path was
// removed (R16/R17 null was a masked ablation). LDS transpose stays.

#define NGRAPHS 4096
constexpr int LDP = 68;    // f32 LDS stride, final MLP
constexpr int LDU = 132;   // f32 LDS stride, 128-wide u tile
constexpr int LDXS = 72;   // bf16 LDS stride (144B rows) for weight + transpose tiles

typedef short bf16x8 __attribute__((ext_vector_type(8)));
typedef float f32x4 __attribute__((ext_vector_type(4)));

union BF8 { bf16x8 v; unsigned u[4]; };

__device__ __forceinline__ unsigned short f2bf(float f) {
    unsigned u = __float_as_uint(f);
    return (unsigned short)((u + 0x7FFFu + ((u >> 16) & 1u)) >> 16);  // RNE
}

__device__ __forceinline__ unsigned cvt_pk_bf16(float lo, float hi) {
    unsigned r;
    asm("v_cvt_pk_bf16_f32 %0, %1, %2" : "=v"(r) : "v"(lo), "v"(hi));
    return r;
}

__device__ __forceinline__ int lower_bound_i(const int* __restrict__ arr, int n, int v) {
    int lo = 0, hi = n;
    while (lo < hi) {
        int mid = (lo + hi) >> 1;
        if (arr[mid] < v) lo = mid + 1; else hi = mid;
    }
    return lo;
}

// one-shot prep: permuted bf16 weights into ws
__global__ __launch_bounds__(256)
void prep_kernel(const float* __restrict__ W1, const float* __restrict__ W2,
                 unsigned short* __restrict__ w1p, unsigned short* __restrict__ w2t) {
    int e = blockIdx.x * 256 + threadIdx.x;     // 0..4095
    int r = e >> 6, k = e & 63;
    int ct = r >> 4, kb = (r >> 2) & 3, reg = r & 3;
    int pi = 32 * (ct >> 1) + 8 * kb + 4 * (ct & 1) + reg;
    w1p[e] = f2bf(W1[k * 64 + pi]);
    w2t[e] = f2bf(W2[k * 64 + r]);
}

// ---------------- attention MLP + weighted scatter ----------------
__global__ __launch_bounds__(256)
void attn_scatter_mfma(const float* __restrict__ x1, const int* __restrict__ batch1, int N1, int nblk1,
                       const float* __restrict__ x2, const int* __restrict__ batch2, int N2,
                       const unsigned short* __restrict__ w1p, const unsigned short* __restrict__ w2t,
                       const float* __restrict__ b1, const float* __restrict__ b2,
                       const float* __restrict__ W3, const float* __restrict__ b3,
                       float* __restrict__ num) {
    __shared__ alignas(16) unsigned short W1L[64 * LDXS];     // bf16, 144B rows (bank-uniform)
    __shared__ alignas(16) unsigned short W2L[64 * LDXS];
    __shared__ alignas(16) float coefF[192];                  // b1 | b2 | W3 (f32)
    __shared__ alignas(16) unsigned short Xs[4][16 * LDXS];   // per-wave transpose medium

    const float* x; const int* batch; int N, col_off, blk;
    if ((int)blockIdx.x < nblk1) { x = x1; batch = batch1; N = N1; col_off = 0;  blk = blockIdx.x; }
    else                         { x = x2; batch = batch2; N = N2; col_off = 64; blk = blockIdx.x - nblk1; }

    const int t = threadIdx.x;
    const int w = t >> 6, l = t & 63;
    const int jj = l & 15, kb = l >> 4;    // MFMA fragment coords
    const int rg = l >> 4, cg = l & 15;    // linear-load coords (row-group / col-group)
    const int base = blk * 256 + w * 64;   // this wave's 64 nodes

    // ---- stage weights (16 KB) + f32 coefficients into LDS ----
    {
        const uint4* s1 = (const uint4*)w1p;      // 512 chunks of 16B
        const uint4* s2 = (const uint4*)w2t;
#pragma unroll
        for (int r = 0; r < 2; ++r) {
            int e4 = t + 256 * r;                 // 0..511
            int row = e4 >> 3, c4 = e4 & 7;       // row 0..63, 16B-chunk 0..7
            *(uint4*)((char*)W1L + row * 144 + c4 * 16) = s1[e4];
            *(uint4*)((char*)W2L + row * 144 + c4 * 16) = s2[e4];
        }
        if (t < 64)       coefF[t] = b1[t];
        else if (t < 128) coefF[t] = b2[t - 64];
        else if (t < 192) coefF[t] = W3[t - 128];
    }
    __syncthreads();

    // ---- batch ids + boundary ballot (wave-uniform 64-bit mask) ----
    const int gball = batch[min(base + l, N - 1)];
    const int gprev = __shfl_up(gball, 1);
    const unsigned long long bal = __ballot(l > 0 && gball != gprev);

    const float b3v = b3[0];
    unsigned short* Xw = Xs[w];

    float ac0 = 0.f, ac1 = 0.f, ac2 = 0.f, ac3 = 0.f;   // cols 4*cg+{0..3}
    int gcur = __shfl(gball, 0);

    // ---- prologue: q=0 contiguous loads (1KB per instruction) ----
    float4 cx0, cx1, cx2, cx3;
    cx0 = cx1 = cx2 = cx3 = make_float4(0.f, 0.f, 0.f, 0.f);
    {
        const int r0 = base + rg;
        if (r0 < N)      cx0 = *(const float4*)&x[(size_t)r0 * 64 + cg * 4];
        const int r1 = base + 4 + rg;
        if (r1 < N)      cx1 = *(const float4*)&x[(size_t)r1 * 64 + cg * 4];
        const int r2 = base + 8 + rg;
        if (r2 < N)      cx2 = *(const float4*)&x[(size_t)r2 * 64 + cg * 4];
        const int r3 = base + 12 + rg;
        if (r3 < N)      cx3 = *(const float4*)&x[(size_t)r3 * 64 + cg * 4];
    }

#pragma unroll
    for (int q = 0; q < 4; ++q) {
        const int nbase = base + q * 16;

        // ---- issue q+1 loads FIRST (independent of current q's chain) ----
        float4 nx0, nx1, nx2, nx3;
        nx0 = nx1 = nx2 = nx3 = make_float4(0.f, 0.f, 0.f, 0.f);
        if (q < 3) {
            const int mb = nbase + 16;
            const int r0 = mb + rg;
            if (r0 < N)      nx0 = *(const float4*)&x[(size_t)r0 * 64 + cg * 4];
            const int r1 = mb + 4 + rg;
            if (r1 < N)      nx1 = *(const float4*)&x[(size_t)r1 * 64 + cg * 4];
            const int r2 = mb + 8 + rg;
            if (r2 < N)      nx2 = *(const float4*)&x[(size_t)r2 * 64 + cg * 4];
            const int r3 = mb + 12 + rg;
            if (r3 < N)      nx3 = *(const float4*)&x[(size_t)r3 * 64 + cg * 4];
        }

        // ---- convert + transpose through wave-private LDS (MFMA operand medium) ----
        {
            uint2 u;
            u.x = cvt_pk_bf16(cx0.x, cx0.y); u.y = cvt_pk_bf16(cx0.z, cx0.w);
            *(uint2*)&Xw[(0 + rg) * LDXS + cg * 4] = u;
            u.x = cvt_pk_bf16(cx1.x, cx1.y); u.y = cvt_pk_bf16(cx1.z, cx1.w);
            *(uint2*)&Xw[(4 + rg) * LDXS + cg * 4] = u;
            u.x = cvt_pk_bf16(cx2.x, cx2.y); u.y = cvt_pk_bf16(cx2.z, cx2.w);
            *(uint2*)&Xw[(8 + rg) * LDXS + cg * 4] = u;
            u.x = cvt_pk_bf16(cx3.x, cx3.y); u.y = cvt_pk_bf16(cx3.z, cx3.w);
            *(uint2*)&Xw[(12 + rg) * LDXS + cg * 4] = u;
        }

        // ---- MFMA A-fragments from LDS (wave-private RAW, compiler lgkmcnt) ----
        const bf16x8 xbl0 = *(const bf16x8*)&Xw[jj * LDXS + kb * 8];
        const bf16x8 xbl1 = *(const bf16x8*)&Xw[jj * LDXS + 32 + kb * 8];

        // ---- layer 1 (swapped): weights from LDS, bias C-init from f32 LDS ----
        unsigned ph[8];
#pragma unroll
        for (int ct = 0; ct < 4; ++ct) {
            const unsigned short* wr = &W1L[(ct * 16 + jj) * LDXS + kb * 8];
            const bf16x8 wf0 = *(const bf16x8*)wr;
            const bf16x8 wf1 = *(const bf16x8*)(wr + 32);
            f32x4 acc = *(const f32x4*)&coefF[32 * (ct >> 1) + 8 * kb + 4 * (ct & 1)];
            acc = __builtin_amdgcn_mfma_f32_16x16x32_bf16(wf0, xbl0, acc, 0, 0, 0);
            acc = __builtin_amdgcn_mfma_f32_16x16x32_bf16(wf1, xbl1, acc, 0, 0, 0);
            ph[2 * ct]     = cvt_pk_bf16(fmaxf(acc[0], 0.f), fmaxf(acc[1], 0.f));
            ph[2 * ct + 1] = cvt_pk_bf16(fmaxf(acc[2], 0.f), fmaxf(acc[3], 0.f));
        }
        BF8 bh0, bh1;
        bh0.u[0] = ph[0]; bh0.u[1] = ph[1]; bh0.u[2] = ph[2]; bh0.u[3] = ph[3];
        bh1.u[0] = ph[4]; bh1.u[1] = ph[5]; bh1.u[2] = ph[6]; bh1.u[3] = ph[7];

        // ---- layer 2+3 (swapped): b2/W3 as f32x4 from LDS ----
        float p = 0.f;
#pragma unroll
        for (int ct = 0; ct < 4; ++ct) {
            const unsigned short* wr = &W2L[(ct * 16 + jj) * LDXS + kb * 8];
            const bf16x8 wf0 = *(const bf16x8*)wr;
            const bf16x8 wf1 = *(const bf16x8*)(wr + 32);
            f32x4 acc = { 0.f, 0.f, 0.f, 0.f };
            acc = __builtin_amdgcn_mfma_f32_16x16x32_bf16(wf0, bh0.v, acc, 0, 0, 0);
            acc = __builtin_amdgcn_mfma_f32_16x16x32_bf16(wf1, bh1.v, acc, 0, 0, 0);
            const f32x4 b2v = *(const f32x4*)&coefF[64 + ct * 16 + 4 * kb];
            const f32x4 w3v = *(const f32x4*)&coefF[128 + ct * 16 + 4 * kb];
            p += fmaxf(acc[0] + b2v[0], 0.f) * w3v[0]
               + fmaxf(acc[1] + b2v[1], 0.f) * w3v[1]
               + fmaxf(acc[2] + b2v[2], 0.f) * w3v[2]
               + fmaxf(acc[3] + b2v[3], 0.f) * w3v[3];
        }
        p += __shfl_xor(p, 16);
        p += __shfl_xor(p, 32);
        const float a = p + b3v;     // a[node nbase+jj], held by lanes with l&15==jj

        // ---- scatter: per-q segment handling (wave-uniform control) ----
        const float a0 = __shfl(a, 0 + rg);
        const float a1 = __shfl(a, 4 + rg);
        const float a2 = __shfl(a, 8 + rg);
        const float a3 = __shfl(a, 12 + rg);
        const unsigned m = (unsigned)((bal >> (q * 16)) & 0xFFFFull);

        if (m == 0u) {
            // whole chunk in gcur's graph (invalid rows have cx==0)
            ac0 += cx0.x * a0 + cx1.x * a1 + cx2.x * a2 + cx3.x * a3;
            ac1 += cx0.y * a0 + cx1.y * a1 + cx2.y * a2 + cx3.y * a3;
            ac2 += cx0.z * a0 + cx1.z * a1 + cx2.z * a2 + cx3.z * a3;
            ac3 += cx0.w * a0 + cx1.w * a1 + cx2.w * a2 + cx3.w * a3;
        } else {
            // wave-uniform segment walk; ~1-2 iterations in practice
            unsigned mm = m;
            int pos = 0;
            while (true) {
                const int nxt = mm ? (__ffs(mm) - 1) : 16;
                // predicated accumulate rows [pos, nxt)
                const float w0 = (rg      >= pos && rg      < nxt) ? a0 : 0.f;
                const float w1 = (4 + rg  >= pos && 4 + rg  < nxt) ? a1 : 0.f;
                const float w2 = (8 + rg  >= pos && 8 + rg  < nxt) ? a2 : 0.f;
                const float w3 = (12 + rg >= pos && 12 + rg < nxt) ? a3 : 0.f;
                ac0 += cx0.x * w0 + cx1.x * w1 + cx2.x * w2 + cx3.x * w3;
                ac1 += cx0.y * w0 + cx1.y * w1 + cx2.y * w2 + cx3.y * w3;
                ac2 += cx0.z * w0 + cx1.z * w1 + cx2.z * w2 + cx3.z * w3;
                ac3 += cx0.w * w0 + cx1.w * w1 + cx2.w * w2 + cx3.w * w3;
                if (nxt == 16) break;
                // flush gcur (reduce over rg lanes; one atomic per lane/feature)
                ac0 += __shfl_xor(ac0, 16); ac0 += __shfl_xor(ac0, 32);
                ac1 += __shfl_xor(ac1, 16); ac1 += __shfl_xor(ac1, 32);
                ac2 += __shfl_xor(ac2, 16); ac2 += __shfl_xor(ac2, 32);
                ac3 += __shfl_xor(ac3, 16); ac3 += __shfl_xor(ac3, 32);
                {
                    float v = ac0;
                    v = (rg == 1) ? ac1 : v;
                    v = (rg == 2) ? ac2 : v;
                    v = (rg == 3) ? ac3 : v;
                    atomicAdd(&num[(size_t)gcur * 128 + col_off + 4 * cg + rg], v);
                }
                ac0 = ac1 = ac2 = ac3 = 0.f;
                gcur = __shfl(gball, q * 16 + nxt);
                mm &= mm - 1;
                pos = nxt;
            }
        }

        // rotate prefetch buffers
        cx0 = nx0; cx1 = nx1; cx2 = nx2; cx3 = nx3;
    }

    // ---- final flush ----
    ac0 += __shfl_xor(ac0, 16); ac0 += __shfl_xor(ac0, 32);
    ac1 += __shfl_xor(ac1, 16); ac1 += __shfl_xor(ac1, 32);
    ac2 += __shfl_xor(ac2, 16); ac2 += __shfl_xor(ac2, 32);
    ac3 += __shfl_xor(ac3, 16); ac3 += __shfl_xor(ac3, 32);
    {
        float v = ac0;
        v = (rg == 1) ? ac1 : v;
        v = (rg == 2) ? ac2 : v;
        v = (rg == 3) ? ac3 : v;
        atomicAdd(&num[(size_t)gcur * 128 + col_off + 4 * cg + rg], v);
    }
}

// ---------------- final MLP (f32, unchanged: negligible time) ----------------
template<int K, int LDAa, int LDBb>
__device__ __forceinline__ void tile_gemm(const float* __restrict__ As,
                                          const float* __restrict__ Bs,
                                          float acc[4][4], int n0, int j0) {
#pragma unroll 4
    for (int k0 = 0; k0 < K; k0 += 4) {
        float4 a[4], wv[4];
#pragma unroll
        for (int i = 0; i < 4; i++) a[i] = *(const float4*)&As[(n0 + i) * LDAa + k0];
#pragma unroll
        for (int kk = 0; kk < 4; kk++) wv[kk] = *(const float4*)&Bs[(k0 + kk) * LDBb + j0];
#pragma unroll
        for (int i = 0; i < 4; i++) {
            const float av0 = a[i].x, av1 = a[i].y, av2 = a[i].z, av3 = a[i].w;
            acc[i][0] += av0 * wv[0].x; acc[i][1] += av0 * wv[0].y; acc[i][2] += av0 * wv[0].z; acc[i][3] += av0 * wv[0].w;
            acc[i][0] += av1 * wv[1].x; acc[i][1] += av1 * wv[1].y; acc[i][2] += av1 * wv[1].z; acc[i][3] += av1 * wv[1].w;
            acc[i][0] += av2 * wv[2].x; acc[i][1] += av2 * wv[2].y; acc[i][2] += av2 * wv[2].z; acc[i][3] += av2 * wv[2].w;
            acc[i][0] += av3 * wv[3].x; acc[i][1] += av3 * wv[3].y; acc[i][2] += av3 * wv[3].z; acc[i][3] += av3 * wv[3].w;
        }
    }
}

__global__ __launch_bounds__(256)
void final_mlp_kernel(const float* __restrict__ num,
                      const int* __restrict__ batch1, int N1,
                      const int* __restrict__ batch2, int N2,
                      const float* __restrict__ W1, const float* __restrict__ b1,  // [128][64]
                      const float* __restrict__ W2, const float* __restrict__ b2,  // [64][64]
                      const float* __restrict__ W3, const float* __restrict__ b3,  // [64][64]
                      float* __restrict__ out) {
    __shared__ float Us[64 * LDU];
    __shared__ float W1s[128 * LDP];
    __shared__ float W2s[64 * LDP];
    __shared__ float W3s[64 * LDP];
    __shared__ float Hs[64 * LDP];
    __shared__ float inv1[64], inv2[64];

    const int t = threadIdx.x;
    const int rowbase = blockIdx.x * 64;

    if (t < 64) {
        int g = rowbase + t;
        int c = lower_bound_i(batch1, N1, g + 1) - lower_bound_i(batch1, N1, g);
        inv1[t] = 1.0f / (float)max(c, 1);
    } else if (t < 128) {
        int g = rowbase + (t - 64);
        int c = lower_bound_i(batch2, N2, g + 1) - lower_bound_i(batch2, N2, g);
        inv2[t - 64] = 1.0f / (float)max(c, 1);
    }

    {
        const float4* W1v = (const float4*)W1;
#pragma unroll
        for (int r = 0; r < 8; r++) {
            int e4 = t + 256 * r;
            int e = e4 * 4;
            int k = e / 64, j = e % 64;
            *(float4*)&W1s[k * LDP + j] = W1v[e4];
        }
        const float4* W2v = (const float4*)W2;
        const float4* W3v = (const float4*)W3;
#pragma unroll
        for (int r = 0; r < 4; r++) {
            int e4 = t + 256 * r;
            int e = e4 * 4;
            int k = e / 64, j = e % 64;
            *(float4*)&W2s[k * LDP + j] = W2v[e4];
            *(float4*)&W3s[k * LDP + j] = W3v[e4];
        }
    }
    __syncthreads();

    {
        const float4* nv = (const float4*)(num + (size_t)rowbase * 128);
#pragma unroll
        for (int r = 0; r < 8; r++) {
            int e4 = t + 256 * r;
            int e = e4 * 4;
            int row = e / 128, col = e % 128;
            float4 v = nv[e4];
            float s = (col < 64) ? inv1[row] : inv2[row];
            v.x *= s; v.y *= s; v.z *= s; v.w *= s;
            *(float4*)&Us[row * LDU + col] = v;
        }
    }
    __syncthreads();

    const int fg = t & 15, ng = t >> 4;
    const int j0 = fg * 4, n0 = ng * 4;

    float acc[4][4];
#pragma unroll
    for (int i = 0; i < 4; i++) { acc[i][0] = 0.f; acc[i][1] = 0.f; acc[i][2] = 0.f; acc[i][3] = 0.f; }
    tile_gemm<128, LDU, LDP>(Us, W1s, acc, n0, j0);
    {
        float4 bb = *(const float4*)&b1[j0];
#pragma unroll
        for (int i = 0; i < 4; i++) {
            float4 hv;
            hv.x = fmaxf(acc[i][0] + bb.x, 0.f);
            hv.y = fmaxf(acc[i][1] + bb.y, 0.f);
            hv.z = fmaxf(acc[i][2] + bb.z, 0.f);
            hv.w = fmaxf(acc[i][3] + bb.w, 0.f);
            *(float4*)&Hs[(n0 + i) * LDP + j0] = hv;
        }
    }
    __syncthreads();

#pragma unroll
    for (int i = 0; i < 4; i++) { acc[i][0] = 0.f; acc[i][1] = 0.f; acc[i][2] = 0.f; acc[i][3] = 0.f; }
    tile_gemm<64, LDP, LDP>(Hs, W2s, acc, n0, j0);
    {
        float4 bb = *(const float4*)&b2[j0];
#pragma unroll
        for (int i = 0; i < 4; i++) {
            float4 hv;
            hv.x = fmaxf(acc[i][0] + bb.x, 0.f);
            hv.y = fmaxf(acc[i][1] + bb.y, 0.f);
            hv.z = fmaxf(acc[i][2] + bb.z, 0.f);
            hv.w = fmaxf(acc[i][3] + bb.w, 0.f);
            *(float4*)&Us[(n0 + i) * LDU + j0] = hv;
        }
    }
    __syncthreads();

#pragma unroll
    for (int i = 0; i < 4; i++) { acc[i][0] = 0.f; acc[i][1] = 0.f; acc[i][2] = 0.f; acc[i][3] = 0.f; }
    tile_gemm<64, LDU, LDP>(Us, W3s, acc, n0, j0);
    {
        float4 bb = *(const float4*)&b3[j0];
#pragma unroll
        for (int i = 0; i < 4; i++) {
            float4 ov;
            ov.x = acc[i][0] + bb.x;
            ov.y = acc[i][1] + bb.y;
            ov.z = acc[i][2] + bb.z;
            ov.w = acc[i][3] + bb.w;
            *(float4*)&out[(size_t)(rowbase + n0 + i) * 64 + j0] = ov;
        }
    }
}

extern "C" void kernel_launch(void* const* d_in, const int* in_sizes, int n_in,
                              void* d_out, int out_size, void* d_ws, size_t ws_size,
                              hipStream_t stream) {
    const float* x1     = (const float*)d_in[0];
    const int*   batch1 = (const int*)d_in[1];
    const float* x2     = (const float*)d_in[2];
    const int*   batch2 = (const int*)d_in[3];
    const float* aW1    = (const float*)d_in[4];
    const float* ab1    = (const float*)d_in[5];
    const float* aW2    = (const float*)d_in[6];
    const float* ab2    = (const float*)d_in[7];
    const float* aW3    = (const float*)d_in[8];
    const float* ab3    = (const float*)d_in[9];
    const float* fW1    = (const float*)d_in[10];
    const float* fb1    = (const float*)d_in[11];
    const float* fW2    = (const float*)d_in[12];
    const float* fb2    = (const float*)d_in[13];
    const float* fW3    = (const float*)d_in[14];
    const float* fb3    = (const float*)d_in[15];

    const int N1 = in_sizes[0] / 64;
    const int N2 = in_sizes[2] / 64;

    // ws layout: [w1p 8KB][w2t 8KB][num f32 4096x128 = 2MB]
    unsigned short* w1p = (unsigned short*)d_ws;
    unsigned short* w2t = w1p + 64 * 64;
    float* num = (float*)((char*)d_ws + 16384);

    prep_kernel<<<dim3(16), dim3(256), 0, stream>>>(aW1, aW2, w1p, w2t);
    hipMemsetAsync(num, 0, (size_t)NGRAPHS * 128 * sizeof(float), stream);

    const int nblk1 = (N1 + 255) / 256;
    const int nblk2 = (N2 + 255) / 256;
    attn_scatter_mfma<<<dim3(nblk1 + nblk2), dim3(256), 0, stream>>>(
        x1, batch1, N1, nblk1, x2, batch2, N2,
        w1p, w2t, ab1, ab2, aW3, ab3, num);
    final_mlp_kernel<<<dim3(NGRAPHS / 64), dim3(256), 0, stream>>>(
        num, batch1, N1, batch2, N2, fW1, fb1, fW2, fb2, fW3, fb3, (float*)d_out);
}

// Round 21
// 128.098 us; speedup vs baseline: 1.3500x; 1.0150x over previous
//
#include <hip/hip_runtime.h>

// ObjectMeanDirectAttention — Round 21: R20 + depth-2 prefetch (8KB/wave in flight,
// each q's loads get ~2 iterations of flight time). Everything else identical to R20
// (contiguous loads -> LDS transpose -> MFMA -> per-q segment scatter).

#define NGRAPHS 4096
constexpr int LDP = 68;    // f32 LDS stride, final MLP
constexpr int LDU = 132;   // f32 LDS stride, 128-wide u tile
constexpr int LDXS = 72;   // bf16 LDS stride (144B rows) for weight + transpose tiles

typedef short bf16x8 __attribute__((ext_vector_type(8)));
typedef float f32x4 __attribute__((ext_vector_type(4)));

union BF8 { bf16x8 v; unsigned u[4]; };

__device__ __forceinline__ unsigned short f2bf(float f) {
    unsigned u = __float_as_uint(f);
    return (unsigned short)((u + 0x7FFFu + ((u >> 16) & 1u)) >> 16);  // RNE
}

__device__ __forceinline__ unsigned cvt_pk_bf16(float lo, float hi) {
    unsigned r;
    asm("v_cvt_pk_bf16_f32 %0, %1, %2" : "=v"(r) : "v"(lo), "v"(hi));
    return r;
}

__device__ __forceinline__ int lower_bound_i(const int* __restrict__ arr, int n, int v) {
    int lo = 0, hi = n;
    while (lo < hi) {
        int mid = (lo + hi) >> 1;
        if (arr[mid] < v) lo = mid + 1; else hi = mid;
    }
    return lo;
}

// one-shot prep: permuted bf16 weights into ws
__global__ __launch_bounds__(256)
void prep_kernel(const float* __restrict__ W1, const float* __restrict__ W2,
                 unsigned short* __restrict__ w1p, unsigned short* __restrict__ w2t) {
    int e = blockIdx.x * 256 + threadIdx.x;     // 0..4095
    int r = e >> 6, k = e & 63;
    int ct = r >> 4, kb = (r >> 2) & 3, reg = r & 3;
    int pi = 32 * (ct >> 1) + 8 * kb + 4 * (ct & 1) + reg;
    w1p[e] = f2bf(W1[k * 64 + pi]);
    w2t[e] = f2bf(W2[k * 64 + r]);
}

// ---------------- attention MLP + weighted scatter ----------------
__global__ __launch_bounds__(256)
void attn_scatter_mfma(const float* __restrict__ x1, const int* __restrict__ batch1, int N1, int nblk1,
                       const float* __restrict__ x2, const int* __restrict__ batch2, int N2,
                       const unsigned short* __restrict__ w1p, const unsigned short* __restrict__ w2t,
                       const float* __restrict__ b1, const float* __restrict__ b2,
                       const float* __restrict__ W3, const float* __restrict__ b3,
                       float* __restrict__ num) {
    __shared__ alignas(16) unsigned short W1L[64 * LDXS];     // bf16, 144B rows (bank-uniform)
    __shared__ alignas(16) unsigned short W2L[64 * LDXS];
    __shared__ alignas(16) float coefF[192];                  // b1 | b2 | W3 (f32)
    __shared__ alignas(16) unsigned short Xs[4][16 * LDXS];   // per-wave transpose medium

    const float* x; const int* batch; int N, col_off, blk;
    if ((int)blockIdx.x < nblk1) { x = x1; batch = batch1; N = N1; col_off = 0;  blk = blockIdx.x; }
    else                         { x = x2; batch = batch2; N = N2; col_off = 64; blk = blockIdx.x - nblk1; }

    const int t = threadIdx.x;
    const int w = t >> 6, l = t & 63;
    const int jj = l & 15, kb = l >> 4;    // MFMA fragment coords
    const int rg = l >> 4, cg = l & 15;    // linear-load coords (row-group / col-group)
    const int base = blk * 256 + w * 64;   // this wave's 64 nodes

    // ---- stage weights (16 KB) + f32 coefficients into LDS ----
    {
        const uint4* s1 = (const uint4*)w1p;      // 512 chunks of 16B
        const uint4* s2 = (const uint4*)w2t;
#pragma unroll
        for (int r = 0; r < 2; ++r) {
            int e4 = t + 256 * r;                 // 0..511
            int row = e4 >> 3, c4 = e4 & 7;       // row 0..63, 16B-chunk 0..7
            *(uint4*)((char*)W1L + row * 144 + c4 * 16) = s1[e4];
            *(uint4*)((char*)W2L + row * 144 + c4 * 16) = s2[e4];
        }
        if (t < 64)       coefF[t] = b1[t];
        else if (t < 128) coefF[t] = b2[t - 64];
        else if (t < 192) coefF[t] = W3[t - 128];
    }
    __syncthreads();

    // ---- batch ids + boundary ballot (wave-uniform 64-bit mask) ----
    const int gball = batch[min(base + l, N - 1)];
    const int gprev = __shfl_up(gball, 1);
    const unsigned long long bal = __ballot(l > 0 && gball != gprev);

    const float b3v = b3[0];
    unsigned short* Xw = Xs[w];

    float ac0 = 0.f, ac1 = 0.f, ac2 = 0.f, ac3 = 0.f;   // cols 4*cg+{0..3}
    int gcur = __shfl(gball, 0);

    // load helper (contiguous: instruction i covers 4 rows = 1KB)
    auto load_tile = [&](int nb, float4& o0, float4& o1, float4& o2, float4& o3) {
        o0 = o1 = o2 = o3 = make_float4(0.f, 0.f, 0.f, 0.f);
        const int r0 = nb + rg;
        if (r0 < N)      o0 = *(const float4*)&x[(size_t)r0 * 64 + cg * 4];
        const int r1 = nb + 4 + rg;
        if (r1 < N)      o1 = *(const float4*)&x[(size_t)r1 * 64 + cg * 4];
        const int r2 = nb + 8 + rg;
        if (r2 < N)      o2 = *(const float4*)&x[(size_t)r2 * 64 + cg * 4];
        const int r3 = nb + 12 + rg;
        if (r3 < N)      o3 = *(const float4*)&x[(size_t)r3 * 64 + cg * 4];
    };

    // ---- prologue: q=0 and q=1 loads in flight ----
    float4 cx0, cx1, cx2, cx3;     // current (q)
    float4 p1x0, p1x1, p1x2, p1x3; // q+1
    load_tile(base, cx0, cx1, cx2, cx3);
    load_tile(base + 16, p1x0, p1x1, p1x2, p1x3);

#pragma unroll
    for (int q = 0; q < 4; ++q) {
        const int nbase = base + q * 16;

        // ---- issue q+2 loads FIRST ----
        float4 p2x0, p2x1, p2x2, p2x3;
        p2x0 = p2x1 = p2x2 = p2x3 = make_float4(0.f, 0.f, 0.f, 0.f);
        if (q < 2) load_tile(nbase + 32, p2x0, p2x1, p2x2, p2x3);

        // ---- convert + transpose through wave-private LDS (MFMA operand medium) ----
        {
            uint2 u;
            u.x = cvt_pk_bf16(cx0.x, cx0.y); u.y = cvt_pk_bf16(cx0.z, cx0.w);
            *(uint2*)&Xw[(0 + rg) * LDXS + cg * 4] = u;
            u.x = cvt_pk_bf16(cx1.x, cx1.y); u.y = cvt_pk_bf16(cx1.z, cx1.w);
            *(uint2*)&Xw[(4 + rg) * LDXS + cg * 4] = u;
            u.x = cvt_pk_bf16(cx2.x, cx2.y); u.y = cvt_pk_bf16(cx2.z, cx2.w);
            *(uint2*)&Xw[(8 + rg) * LDXS + cg * 4] = u;
            u.x = cvt_pk_bf16(cx3.x, cx3.y); u.y = cvt_pk_bf16(cx3.z, cx3.w);
            *(uint2*)&Xw[(12 + rg) * LDXS + cg * 4] = u;
        }

        // ---- MFMA A-fragments from LDS (wave-private RAW, compiler lgkmcnt) ----
        const bf16x8 xbl0 = *(const bf16x8*)&Xw[jj * LDXS + kb * 8];
        const bf16x8 xbl1 = *(const bf16x8*)&Xw[jj * LDXS + 32 + kb * 8];

        // ---- layer 1 (swapped): weights from LDS, bias C-init from f32 LDS ----
        unsigned ph[8];
#pragma unroll
        for (int ct = 0; ct < 4; ++ct) {
            const unsigned short* wr = &W1L[(ct * 16 + jj) * LDXS + kb * 8];
            const bf16x8 wf0 = *(const bf16x8*)wr;
            const bf16x8 wf1 = *(const bf16x8*)(wr + 32);
            f32x4 acc = *(const f32x4*)&coefF[32 * (ct >> 1) + 8 * kb + 4 * (ct & 1)];
            acc = __builtin_amdgcn_mfma_f32_16x16x32_bf16(wf0, xbl0, acc, 0, 0, 0);
            acc = __builtin_amdgcn_mfma_f32_16x16x32_bf16(wf1, xbl1, acc, 0, 0, 0);
            ph[2 * ct]     = cvt_pk_bf16(fmaxf(acc[0], 0.f), fmaxf(acc[1], 0.f));
            ph[2 * ct + 1] = cvt_pk_bf16(fmaxf(acc[2], 0.f), fmaxf(acc[3], 0.f));
        }
        BF8 bh0, bh1;
        bh0.u[0] = ph[0]; bh0.u[1] = ph[1]; bh0.u[2] = ph[2]; bh0.u[3] = ph[3];
        bh1.u[0] = ph[4]; bh1.u[1] = ph[5]; bh1.u[2] = ph[6]; bh1.u[3] = ph[7];

        // ---- layer 2+3 (swapped): b2/W3 as f32x4 from LDS ----
        float p = 0.f;
#pragma unroll
        for (int ct = 0; ct < 4; ++ct) {
            const unsigned short* wr = &W2L[(ct * 16 + jj) * LDXS + kb * 8];
            const bf16x8 wf0 = *(const bf16x8*)wr;
            const bf16x8 wf1 = *(const bf16x8*)(wr + 32);
            f32x4 acc = { 0.f, 0.f, 0.f, 0.f };
            acc = __builtin_amdgcn_mfma_f32_16x16x32_bf16(wf0, bh0.v, acc, 0, 0, 0);
            acc = __builtin_amdgcn_mfma_f32_16x16x32_bf16(wf1, bh1.v, acc, 0, 0, 0);
            const f32x4 b2v = *(const f32x4*)&coefF[64 + ct * 16 + 4 * kb];
            const f32x4 w3v = *(const f32x4*)&coefF[128 + ct * 16 + 4 * kb];
            p += fmaxf(acc[0] + b2v[0], 0.f) * w3v[0]
               + fmaxf(acc[1] + b2v[1], 0.f) * w3v[1]
               + fmaxf(acc[2] + b2v[2], 0.f) * w3v[2]
               + fmaxf(acc[3] + b2v[3], 0.f) * w3v[3];
        }
        p += __shfl_xor(p, 16);
        p += __shfl_xor(p, 32);
        const float a = p + b3v;     // a[node nbase+jj], held by lanes with l&15==jj

        // ---- scatter: per-q segment handling (wave-uniform control) ----
        const float a0 = __shfl(a, 0 + rg);
        const float a1 = __shfl(a, 4 + rg);
        const float a2 = __shfl(a, 8 + rg);
        const float a3 = __shfl(a, 12 + rg);
        const unsigned m = (unsigned)((bal >> (q * 16)) & 0xFFFFull);

        if (m == 0u) {
            ac0 += cx0.x * a0 + cx1.x * a1 + cx2.x * a2 + cx3.x * a3;
            ac1 += cx0.y * a0 + cx1.y * a1 + cx2.y * a2 + cx3.y * a3;
            ac2 += cx0.z * a0 + cx1.z * a1 + cx2.z * a2 + cx3.z * a3;
            ac3 += cx0.w * a0 + cx1.w * a1 + cx2.w * a2 + cx3.w * a3;
        } else {
            unsigned mm = m;
            int pos = 0;
            while (true) {
                const int nxt = mm ? (__ffs(mm) - 1) : 16;
                const float w0 = (rg      >= pos && rg      < nxt) ? a0 : 0.f;
                const float w1 = (4 + rg  >= pos && 4 + rg  < nxt) ? a1 : 0.f;
                const float w2 = (8 + rg  >= pos && 8 + rg  < nxt) ? a2 : 0.f;
                const float w3 = (12 + rg >= pos && 12 + rg < nxt) ? a3 : 0.f;
                ac0 += cx0.x * w0 + cx1.x * w1 + cx2.x * w2 + cx3.x * w3;
                ac1 += cx0.y * w0 + cx1.y * w1 + cx2.y * w2 + cx3.y * w3;
                ac2 += cx0.z * w0 + cx1.z * w1 + cx2.z * w2 + cx3.z * w3;
                ac3 += cx0.w * w0 + cx1.w * w1 + cx2.w * w2 + cx3.w * w3;
                if (nxt == 16) break;
                ac0 += __shfl_xor(ac0, 16); ac0 += __shfl_xor(ac0, 32);
                ac1 += __shfl_xor(ac1, 16); ac1 += __shfl_xor(ac1, 32);
                ac2 += __shfl_xor(ac2, 16); ac2 += __shfl_xor(ac2, 32);
                ac3 += __shfl_xor(ac3, 16); ac3 += __shfl_xor(ac3, 32);
                {
                    float v = ac0;
                    v = (rg == 1) ? ac1 : v;
                    v = (rg == 2) ? ac2 : v;
                    v = (rg == 3) ? ac3 : v;
                    atomicAdd(&num[(size_t)gcur * 128 + col_off + 4 * cg + rg], v);
                }
                ac0 = ac1 = ac2 = ac3 = 0.f;
                gcur = __shfl(gball, q * 16 + nxt);
                mm &= mm - 1;
                pos = nxt;
            }
        }

        // rotate prefetch buffers: current <- q+1, q+1 <- q+2
        cx0 = p1x0; cx1 = p1x1; cx2 = p1x2; cx3 = p1x3;
        p1x0 = p2x0; p1x1 = p2x1; p1x2 = p2x2; p1x3 = p2x3;
    }

    // ---- final flush ----
    ac0 += __shfl_xor(ac0, 16); ac0 += __shfl_xor(ac0, 32);
    ac1 += __shfl_xor(ac1, 16); ac1 += __shfl_xor(ac1, 32);
    ac2 += __shfl_xor(ac2, 16); ac2 += __shfl_xor(ac2, 32);
    ac3 += __shfl_xor(ac3, 16); ac3 += __shfl_xor(ac3, 32);
    {
        float v = ac0;
        v = (rg == 1) ? ac1 : v;
        v = (rg == 2) ? ac2 : v;
        v = (rg == 3) ? ac3 : v;
        atomicAdd(&num[(size_t)gcur * 128 + col_off + 4 * cg + rg], v);
    }
}

// ---------------- final MLP (f32, unchanged: negligible time) ----------------
template<int K, int LDAa, int LDBb>
__device__ __forceinline__ void tile_gemm(const float* __restrict__ As,
                                          const float* __restrict__ Bs,
                                          float acc[4][4], int n0, int j0) {
#pragma unroll 4
    for (int k0 = 0; k0 < K; k0 += 4) {
        float4 a[4], wv[4];
#pragma unroll
        for (int i = 0; i < 4; i++) a[i] = *(const float4*)&As[(n0 + i) * LDAa + k0];
#pragma unroll
        for (int kk = 0; kk < 4; kk++) wv[kk] = *(const float4*)&Bs[(k0 + kk) * LDBb + j0];
#pragma unroll
        for (int i = 0; i < 4; i++) {
            const float av0 = a[i].x, av1 = a[i].y, av2 = a[i].z, av3 = a[i].w;
            acc[i][0] += av0 * wv[0].x; acc[i][1] += av0 * wv[0].y; acc[i][2] += av0 * wv[0].z; acc[i][3] += av0 * wv[0].w;
            acc[i][0] += av1 * wv[1].x; acc[i][1] += av1 * wv[1].y; acc[i][2] += av1 * wv[1].z; acc[i][3] += av1 * wv[1].w;
            acc[i][0] += av2 * wv[2].x; acc[i][1] += av2 * wv[2].y; acc[i][2] += av2 * wv[2].z; acc[i][3] += av2 * wv[2].w;
            acc[i][0] += av3 * wv[3].x; acc[i][1] += av3 * wv[3].y; acc[i][2] += av3 * wv[3].z; acc[i][3] += av3 * wv[3].w;
        }
    }
}

__global__ __launch_bounds__(256)
void final_mlp_kernel(const float* __restrict__ num,
                      const int* __restrict__ batch1, int N1,
                      const int* __restrict__ batch2, int N2,
                      const float* __restrict__ W1, const float* __restrict__ b1,  // [128][64]
                      const float* __restrict__ W2, const float* __restrict__ b2,  // [64][64]
                      const float* __restrict__ W3, const float* __restrict__ b3,  // [64][64]
                      float* __restrict__ out) {
    __shared__ float Us[64 * LDU];
    __shared__ float W1s[128 * LDP];
    __shared__ float W2s[64 * LDP];
    __shared__ float W3s[64 * LDP];
    __shared__ float Hs[64 * LDP];
    __shared__ float inv1[64], inv2[64];

    const int t = threadIdx.x;
    const int rowbase = blockIdx.x * 64;

    if (t < 64) {
        int g = rowbase + t;
        int c = lower_bound_i(batch1, N1, g + 1) - lower_bound_i(batch1, N1, g);
        inv1[t] = 1.0f / (float)max(c, 1);
    } else if (t < 128) {
        int g = rowbase + (t - 64);
        int c = lower_bound_i(batch2, N2, g + 1) - lower_bound_i(batch2, N2, g);
        inv2[t - 64] = 1.0f / (float)max(c, 1);
    }

    {
        const float4* W1v = (const float4*)W1;
#pragma unroll
        for (int r = 0; r < 8; r++) {
            int e4 = t + 256 * r;
            int e = e4 * 4;
            int k = e / 64, j = e % 64;
            *(float4*)&W1s[k * LDP + j] = W1v[e4];
        }
        const float4* W2v = (const float4*)W2;
        const float4* W3v = (const float4*)W3;
#pragma unroll
        for (int r = 0; r < 4; r++) {
            int e4 = t + 256 * r;
            int e = e4 * 4;
            int k = e / 64, j = e % 64;
            *(float4*)&W2s[k * LDP + j] = W2v[e4];
            *(float4*)&W3s[k * LDP + j] = W3v[e4];
        }
    }
    __syncthreads();

    {
        const float4* nv = (const float4*)(num + (size_t)rowbase * 128);
#pragma unroll
        for (int r = 0; r < 8; r++) {
            int e4 = t + 256 * r;
            int e = e4 * 4;
            int row = e / 128, col = e % 128;
            float4 v = nv[e4];
            float s = (col < 64) ? inv1[row] : inv2[row];
            v.x *= s; v.y *= s; v.z *= s; v.w *= s;
            *(float4*)&Us[row * LDU + col] = v;
        }
    }
    __syncthreads();

    const int fg = t & 15, ng = t >> 4;
    const int j0 = fg * 4, n0 = ng * 4;

    float acc[4][4];
#pragma unroll
    for (int i = 0; i < 4; i++) { acc[i][0] = 0.f; acc[i][1] = 0.f; acc[i][2] = 0.f; acc[i][3] = 0.f; }
    tile_gemm<128, LDU, LDP>(Us, W1s, acc, n0, j0);
    {
        float4 bb = *(const float4*)&b1[j0];
#pragma unroll
        for (int i = 0; i < 4; i++) {
            float4 hv;
            hv.x = fmaxf(acc[i][0] + bb.x, 0.f);
            hv.y = fmaxf(acc[i][1] + bb.y, 0.f);
            hv.z = fmaxf(acc[i][2] + bb.z, 0.f);
            hv.w = fmaxf(acc[i][3] + bb.w, 0.f);
            *(float4*)&Hs[(n0 + i) * LDP + j0] = hv;
        }
    }
    __syncthreads();

#pragma unroll
    for (int i = 0; i < 4; i++) { acc[i][0] = 0.f; acc[i][1] = 0.f; acc[i][2] = 0.f; acc[i][3] = 0.f; }
    tile_gemm<64, LDP, LDP>(Hs, W2s, acc, n0, j0);
    {
        float4 bb = *(const float4*)&b2[j0];
#pragma unroll
        for (int i = 0; i < 4; i++) {
            float4 hv;
            hv.x = fmaxf(acc[i][0] + bb.x, 0.f);
            hv.y = fmaxf(acc[i][1] + bb.y, 0.f);
            hv.z = fmaxf(acc[i][2] + bb.z, 0.f);
            hv.w = fmaxf(acc[i][3] + bb.w, 0.f);
            *(float4*)&Us[(n0 + i) * LDU + j0] = hv;
        }
    }
    __syncthreads();

#pragma unroll
    for (int i = 0; i < 4; i++) { acc[i][0] = 0.f; acc[i][1] = 0.f; acc[i][2] = 0.f; acc[i][3] = 0.f; }
    tile_gemm<64, LDU, LDP>(Us, W3s, acc, n0, j0);
    {
        float4 bb = *(const float4*)&b3[j0];
#pragma unroll
        for (int i = 0; i < 4; i++) {
            float4 ov;
            ov.x = acc[i][0] + bb.x;
            ov.y = acc[i][1] + bb.y;
            ov.z = acc[i][2] + bb.z;
            ov.w = acc[i][3] + bb.w;
            *(float4*)&out[(size_t)(rowbase + n0 + i) * 64 + j0] = ov;
        }
    }
}

extern "C" void kernel_launch(void* const* d_in, const int* in_sizes, int n_in,
                              void* d_out, int out_size, void* d_ws, size_t ws_size,
                              hipStream_t stream) {
    const float* x1     = (const float*)d_in[0];
    const int*   batch1 = (const int*)d_in[1];
    const float* x2     = (const float*)d_in[2];
    const int*   batch2 = (const int*)d_in[3];
    const float* aW1    = (const float*)d_in[4];
    const float* ab1    = (const float*)d_in[5];
    const float* aW2    = (const float*)d_in[6];
    const float* ab2    = (const float*)d_in[7];
    const float* aW3    = (const float*)d_in[8];
    const float* ab3    = (const float*)d_in[9];
    const float* fW1    = (const float*)d_in[10];
    const float* fb1    = (const float*)d_in[11];
    const float* fW2    = (const float*)d_in[12];
    const float* fb2    = (const float*)d_in[13];
    const float* fW3    = (const float*)d_in[14];
    const float* fb3    = (const float*)d_in[15];

    const int N1 = in_sizes[0] / 64;
    const int N2 = in_sizes[2] / 64;

    // ws layout: [w1p 8KB][w2t 8KB][num f32 4096x128 = 2MB]
    unsigned short* w1p = (unsigned short*)d_ws;
    unsigned short* w2t = w1p + 64 * 64;
    float* num = (float*)((char*)d_ws + 16384);

    prep_kernel<<<dim3(16), dim3(256), 0, stream>>>(aW1, aW2, w1p, w2t);
    hipMemsetAsync(num, 0, (size_t)NGRAPHS * 128 * sizeof(float), stream);

    const int nblk1 = (N1 + 255) / 256;
    const int nblk2 = (N2 + 255) / 256;
    attn_scatter_mfma<<<dim3(nblk1 + nblk2), dim3(256), 0, stream>>>(
        x1, batch1, N1, nblk1, x2, batch2, N2,
        w1p, w2t, ab1, ab2, aW3, ab3, num);
    final_mlp_kernel<<<dim3(NGRAPHS / 64), dim3(256), 0, stream>>>(
        num, batch1, N1, batch2, N2, fW1, fb1, fW2, fb2, fW3, fb3, (float*)d_out);
}